// Round 4
// baseline (690.970 us; speedup 1.0000x reference)
//
#include <hip/hip_runtime.h>
#include <hip/hip_bf16.h>

typedef short short8 __attribute__((ext_vector_type(8)));
typedef float floatx4 __attribute__((ext_vector_type(4)));

#define MFMA_BF16(A, B, C) __builtin_amdgcn_mfma_f32_16x16x32_bf16((A), (B), (C), 0, 0, 0)

__device__ __forceinline__ float bf2f(const __hip_bfloat16 v) { return __bfloat162float(v); }
__device__ __forceinline__ short f2bf_s(float f) {
    __hip_bfloat16 h = __float2bfloat16(f);
    return __builtin_bit_cast(short, h);
}
__device__ __forceinline__ float sigmoidf_(float x) { return 1.0f / (1.0f + __expf(-x)); }
__device__ __forceinline__ float tanhf_(float x) { return 1.0f - 2.0f / (__expf(2.0f * x) + 1.0f); }

// pack 8 fp32 (two float4) -> bf16 short8 MFMA frag
__device__ __forceinline__ short8 cvt8(const float4 a, const float4 b) {
    short8 r;
    r[0] = f2bf_s(a.x); r[1] = f2bf_s(a.y); r[2] = f2bf_s(a.z); r[3] = f2bf_s(a.w);
    r[4] = f2bf_s(b.x); r[5] = f2bf_s(b.y); r[6] = f2bf_s(b.z); r[7] = f2bf_s(b.w);
    return r;
}

// ---------------------------------------------------------------------------
// Kernel 1: GRU over T=128, batch rows BJ=5120. 16 rows per block, 4 waves,
// each wave owns 32 cols of each of the 3 gates (96 of 384 output cols).
// FP32 inputs -> in-kernel bf16 MFMA frags; fp32 accumulators/gates; h kept
// fp32 in registers for the z*h term, bf16 in LDS for the W_hh contraction.
// ROUND 4: output dtype fixed to FP32 (reference output is float32).
// ---------------------------------------------------------------------------
__global__ __launch_bounds__(256) void gru_kernel(
    const float* __restrict__ obs,   // [1024,128,5,64] fp32
    const float* __restrict__ W_ih,  // [384,64]
    const float* __restrict__ W_hh,  // [384,128]
    const float* __restrict__ b_ih,  // [384]
    const float* __restrict__ b_hh,  // [384]
    __hip_bfloat16* __restrict__ h_out)  // [5120,128] bf16 (internal ws)
{
    // LDS h: 2 buffers x 16 rows x 136 shorts (272B stride: banks spread evenly)
    __shared__ alignas(16) short h_lds[2 * 16 * 136];

    const int tid = threadIdx.x;
    const int w = tid >> 6;          // wave 0..3
    const int lane = tid & 63;
    const int q = lane >> 4;         // quad 0..3
    const int c = lane & 15;
    const int r0 = blockIdx.x * 16;  // first global row of this block

    // zero BOTH h buffers
    for (int i = tid; i < 2 * 16 * 136; i += 256) h_lds[i] = 0;

    // ---- load weight B-frags (fp32 -> bf16): B[k][n] = W[colbase+n][k],
    //      lane holds n=c, k=8q+j
    short8 wih[3][2][2];  // [gate][u][f]  K=64  -> 2 frags
    short8 whh[3][2][4];  // [gate][u][f]  K=128 -> 4 frags
#pragma unroll
    for (int g = 0; g < 3; ++g)
#pragma unroll
        for (int u = 0; u < 2; ++u) {
            const int col = g * 128 + w * 32 + u * 16 + c;
#pragma unroll
            for (int f = 0; f < 2; ++f) {
                const float4 a = *reinterpret_cast<const float4*>(W_ih + col * 64 + f * 32 + q * 8);
                const float4 b = *reinterpret_cast<const float4*>(W_ih + col * 64 + f * 32 + q * 8 + 4);
                wih[g][u][f] = cvt8(a, b);
            }
#pragma unroll
            for (int f = 0; f < 4; ++f) {
                const float4 a = *reinterpret_cast<const float4*>(W_hh + col * 128 + f * 32 + q * 8);
                const float4 b = *reinterpret_cast<const float4*>(W_hh + col * 128 + f * 32 + q * 8 + 4);
                whh[g][u][f] = cvt8(a, b);
            }
        }

    // ---- biases per owned column (same for all 4 acc rows)
    float bias_r[2], bias_z[2], bias_in[2], bias_hn[2];
#pragma unroll
    for (int u = 0; u < 2; ++u) {
        const int cc = w * 32 + u * 16 + c;
        bias_r[u]  = b_ih[cc]       + b_hh[cc];
        bias_z[u]  = b_ih[128 + cc] + b_hh[128 + cc];
        bias_in[u] = b_ih[256 + cc];
        bias_hn[u] = b_hh[256 + cc];
    }

    // ---- x addressing: A-frag lane holds row m=c (global row r0+c), k=32f+8q+j
    const int r = r0 + c;
    const int bb = r / 5;
    const int jj = r - bb * 5;
    const float* xg = obs + bb * 40960 + jj * 64 + q * 8;

    float h_keep[2][4];
#pragma unroll
    for (int u = 0; u < 2; ++u)
#pragma unroll
        for (int i = 0; i < 4; ++i) h_keep[u][i] = 0.0f;

    // preload x for t=0
    float4 xa0 = *reinterpret_cast<const float4*>(xg);
    float4 xa1 = *reinterpret_cast<const float4*>(xg + 4);
    float4 xa2 = *reinterpret_cast<const float4*>(xg + 32);
    float4 xa3 = *reinterpret_cast<const float4*>(xg + 36);
    short8 xc0 = cvt8(xa0, xa1);
    short8 xc1 = cvt8(xa2, xa3);

    __syncthreads();  // h buffers zeroed

    int bufo = 0;
    for (int t = 0; t < 128; ++t) {
        const int nbufo = 2176 - bufo;
        const short* hb = &h_lds[bufo];

        // h A-frags: lane holds row m=c, k=32f+8q+j
        short8 hf[4];
#pragma unroll
        for (int f = 0; f < 4; ++f)
            hf[f] = *reinterpret_cast<const short8*>(hb + c * 136 + f * 32 + q * 8);

        // prefetch x for t+1 (clamped); latency overlaps MFMA + elementwise
        const int tp = (t + 1) > 127 ? 127 : (t + 1);
        const float4 xb0 = *reinterpret_cast<const float4*>(xg + tp * 320);
        const float4 xb1 = *reinterpret_cast<const float4*>(xg + tp * 320 + 4);
        const float4 xb2 = *reinterpret_cast<const float4*>(xg + tp * 320 + 32);
        const float4 xb3 = *reinterpret_cast<const float4*>(xg + tp * 320 + 36);

        floatx4 ar[2], az[2], ain[2], ahn[2];
#pragma unroll
        for (int u = 0; u < 2; ++u) {
            ar[u]  = (floatx4){bias_r[u],  bias_r[u],  bias_r[u],  bias_r[u]};
            az[u]  = (floatx4){bias_z[u],  bias_z[u],  bias_z[u],  bias_z[u]};
            ain[u] = (floatx4){bias_in[u], bias_in[u], bias_in[u], bias_in[u]};
            ahn[u] = (floatx4){bias_hn[u], bias_hn[u], bias_hn[u], bias_hn[u]};
            // gi (K=64)
            ar[u]  = MFMA_BF16(xc0, wih[0][u][0], ar[u]);
            ar[u]  = MFMA_BF16(xc1, wih[0][u][1], ar[u]);
            az[u]  = MFMA_BF16(xc0, wih[1][u][0], az[u]);
            az[u]  = MFMA_BF16(xc1, wih[1][u][1], az[u]);
            ain[u] = MFMA_BF16(xc0, wih[2][u][0], ain[u]);
            ain[u] = MFMA_BF16(xc1, wih[2][u][1], ain[u]);
            // gh (K=128)
#pragma unroll
            for (int f = 0; f < 4; ++f) {
                ar[u]  = MFMA_BF16(hf[f], whh[0][u][f], ar[u]);
                az[u]  = MFMA_BF16(hf[f], whh[1][u][f], az[u]);
                ahn[u] = MFMA_BF16(hf[f], whh[2][u][f], ahn[u]);
            }
        }

        // elementwise GRU update; C/D layout: col = c (+tile), row = 4q + i
        short* hnb = &h_lds[nbufo];
#pragma unroll
        for (int u = 0; u < 2; ++u)
#pragma unroll
            for (int i = 0; i < 4; ++i) {
                const float rr = sigmoidf_(ar[u][i]);
                const float zz = sigmoidf_(az[u][i]);
                const float nn = tanhf_(ain[u][i] + rr * ahn[u][i]);
                const float hv = (1.0f - zz) * nn + zz * h_keep[u][i];
                h_keep[u][i] = hv;
                hnb[(4 * q + i) * 136 + w * 32 + u * 16 + c] = f2bf_s(hv);
            }

        xc0 = cvt8(xb0, xb1);
        xc1 = cvt8(xb2, xb3);
        bufo = nbufo;
        __syncthreads();
    }

    // final hidden -> global (bf16 ws), rows r0+4q+i, cols w*32+u*16+c
#pragma unroll
    for (int u = 0; u < 2; ++u)
#pragma unroll
        for (int i = 0; i < 4; ++i)
            h_out[(r0 + 4 * q + i) * 128 + w * 32 + u * 16 + c] = __float2bfloat16(h_keep[u][i]);
}

// ---------------------------------------------------------------------------
// Kernel 2: GAT (fixed 5-chain, self-loops) + trunk MLP + actor/critic heads.
// One block per 4 batch elements (20 rows), fp32 VALU, LDS-staged activations.
// ROUND 4: fp32 output writes.
// ---------------------------------------------------------------------------
__global__ __launch_bounds__(256) void head_kernel(
    const __hip_bfloat16* __restrict__ h_in,  // [5120,128] bf16 ws
    const float* __restrict__ gat_W,    // [128,128]
    const float* __restrict__ att_src,  // [4,32]
    const float* __restrict__ att_dst,  // [4,32]
    const float* __restrict__ gat_b,    // [128]
    const float* __restrict__ W1,       // [128,128]
    const float* __restrict__ b1,       // [128]
    const float* __restrict__ W2,       // [128,64]
    const float* __restrict__ b2,       // [64]
    const float* __restrict__ actor_W,  // [5,64,4]
    const float* __restrict__ actor_b,  // [5,4]
    const float* __restrict__ critic_W, // [64]
    const float* __restrict__ critic_b, // [1]
    float* __restrict__ out)            // logits[1024*5*4] ++ value[1024], fp32
{
    __shared__ float hs[20][128];
    __shared__ float xp[20][128];
    __shared__ float gs[20][128];
    __shared__ float t1[20][128];
    __shared__ float t2[20][64];
    __shared__ float as_[20][4];
    __shared__ float ad_[20][4];

    const int tid = threadIdx.x;
    const int b0 = blockIdx.x * 4;
    const int rbase = b0 * 5;

    // load h (20 rows x 128)
    for (int i = tid; i < 20 * 128; i += 256)
        hs[i >> 7][i & 127] = bf2f(h_in[rbase * 128 + i]);
    __syncthreads();

    // xp = h @ gat_W
#pragma unroll
    for (int it = 0; it < 10; ++it) {
        const int row = it * 2 + (tid >> 7);
        const int col = tid & 127;
        float acc = 0.0f;
#pragma unroll 8
        for (int k = 0; k < 128; ++k)
            acc += hs[row][k] * gat_W[k * 128 + col];
        xp[row][col] = acc;
    }
    __syncthreads();

    // per-node attention scores
    if (tid < 160) {
        const int row = tid >> 3;
        const int hd = (tid >> 1) & 3;
        const int which = tid & 1;
        const float* att = which ? att_dst : att_src;
        float acc = 0.0f;
#pragma unroll
        for (int d = 0; d < 32; ++d) acc += xp[row][hd * 32 + d] * att[hd * 32 + d];
        if (which) ad_[row][hd] = acc; else as_[row][hd] = acc;
    }
    __syncthreads();

    // softmax over chain neighbors {i-1,i,i+1} and aggregate
    for (int i = tid; i < 20 * 128; i += 256) {
        const int row = i >> 7, col = i & 127, hd = col >> 5;
        const int bb = row / 5, dst = row - bb * 5, jbase = bb * 5;
        const float adv = ad_[row][hd];
        float ev[3]; int js[3]; int cnt = 0; float mx = -1e30f;
#pragma unroll
        for (int dj = -1; dj <= 1; ++dj) {
            const int j = dst + dj;
            if (j < 0 || j >= 5) continue;
            float e = as_[jbase + j][hd] + adv;
            e = e > 0.0f ? e : 0.2f * e;   // leaky_relu 0.2
            js[cnt] = j; ev[cnt] = e; mx = fmaxf(mx, e); ++cnt;
        }
        float s = 0.0f, num = 0.0f;
        for (int k = 0; k < cnt; ++k) {
            const float a = __expf(ev[k] - mx);
            s += a; num += a * xp[jbase + js[k]][col];
        }
        gs[row][col] = num / s + gat_b[col];
    }
    __syncthreads();

    // t1 = relu(g @ W1 + b1)
#pragma unroll
    for (int it = 0; it < 10; ++it) {
        const int row = it * 2 + (tid >> 7);
        const int col = tid & 127;
        float acc = b1[col];
#pragma unroll 8
        for (int k = 0; k < 128; ++k)
            acc += gs[row][k] * W1[k * 128 + col];
        t1[row][col] = fmaxf(acc, 0.0f);
    }
    __syncthreads();

    // t2 = relu(t1 @ W2 + b2)
    for (int i = tid; i < 20 * 64; i += 256) {
        const int row = i >> 6, col = i & 63;
        float acc = b2[col];
#pragma unroll 8
        for (int k = 0; k < 128; ++k)
            acc += t1[row][k] * W2[k * 64 + col];
        t2[row][col] = fmaxf(acc, 0.0f);
    }
    __syncthreads();

    // actor logits
    if (tid < 80) {
        const int row = tid >> 2, p = tid & 3;
        const int j = row % 5;
        float acc = actor_b[j * 4 + p];
#pragma unroll
        for (int o = 0; o < 64; ++o)
            acc += t2[row][o] * actor_W[j * 256 + o * 4 + p];
        out[(rbase + row) * 4 + p] = acc;
    }
    // critic on junction mean
    if (tid >= 128 && tid < 132) {
        const int bb = tid - 128;
        float acc = 0.0f;
#pragma unroll
        for (int o = 0; o < 64; ++o) {
            float m = 0.0f;
#pragma unroll
            for (int j = 0; j < 5; ++j) m += t2[bb * 5 + j][o];
            acc += (m * 0.2f) * critic_W[o];
        }
        out[20480 + b0 + bb] = acc + critic_b[0];
    }
}

extern "C" void kernel_launch(void* const* d_in, const int* in_sizes, int n_in,
                              void* d_out, int out_size, void* d_ws, size_t ws_size,
                              hipStream_t stream) {
    (void)in_sizes; (void)n_in; (void)out_size; (void)ws_size;
    const float* obs      = (const float*)d_in[0];
    // d_in[1] = edge_index (int32; fixed bidirectional 5-chain baked into kernel 2)
    const float* W_ih     = (const float*)d_in[2];
    const float* W_hh     = (const float*)d_in[3];
    const float* b_ih     = (const float*)d_in[4];
    const float* b_hh     = (const float*)d_in[5];
    const float* gat_W    = (const float*)d_in[6];
    const float* att_src  = (const float*)d_in[7];
    const float* att_dst  = (const float*)d_in[8];
    const float* gat_b    = (const float*)d_in[9];
    const float* W1       = (const float*)d_in[10];
    const float* b1       = (const float*)d_in[11];
    const float* W2       = (const float*)d_in[12];
    const float* b2       = (const float*)d_in[13];
    const float* actor_W  = (const float*)d_in[14];
    const float* actor_b  = (const float*)d_in[15];
    const float* critic_W = (const float*)d_in[16];
    const float* critic_b = (const float*)d_in[17];

    __hip_bfloat16* h_ws = (__hip_bfloat16*)d_ws;  // [5120,128] bf16 = 1.31 MB

    gru_kernel<<<320, 256, 0, stream>>>(obs, W_ih, W_hh, b_ih, b_hh, h_ws);
    head_kernel<<<256, 256, 0, stream>>>(h_ws, gat_W, att_src, att_dst, gat_b,
                                         W1, b1, W2, b2, actor_W, actor_b,
                                         critic_W, critic_b,
                                         (float*)d_out);
}

// Round 5
// 553.916 us; speedup vs baseline: 1.2474x; 1.2474x over previous
//
#include <hip/hip_runtime.h>
#include <hip/hip_bf16.h>

typedef short short8 __attribute__((ext_vector_type(8)));
typedef float floatx4 __attribute__((ext_vector_type(4)));

#define MFMA_BF16(A, B, C) __builtin_amdgcn_mfma_f32_16x16x32_bf16((A), (B), (C), 0, 0, 0)
#define LOG2E 1.44269504088896340736f

__device__ __forceinline__ float bf2f(const __hip_bfloat16 v) { return __bfloat162float(v); }

// branchless RNE fp32->bf16 (inputs finite by construction; no NaN path needed)
__device__ __forceinline__ unsigned rne_bits(float f) {
    unsigned u = __builtin_bit_cast(unsigned, f);
    return u + 0x7fffu + ((u >> 16) & 1u);
}
__device__ __forceinline__ unsigned pack_bf16(float a, float b) {
    return (rne_bits(b) & 0xffff0000u) | (rne_bits(a) >> 16);
}
__device__ __forceinline__ short bf16_s(float f) { return (short)(rne_bits(f) >> 16); }

// pack 8 fp32 (two float4) -> bf16 short8 MFMA frag
__device__ __forceinline__ short8 cvt8(const float4 a, const float4 b) {
    union { unsigned u[4]; short8 s; } r;
    r.u[0] = pack_bf16(a.x, a.y);
    r.u[1] = pack_bf16(a.z, a.w);
    r.u[2] = pack_bf16(b.x, b.y);
    r.u[3] = pack_bf16(b.z, b.w);
    return r.s;
}

// fast sigmoid/tanh: v_exp_f32 + v_rcp_f32 (<=2ulp each; output squashed, err ~1e-7)
__device__ __forceinline__ float fast_sigmoid(float x) {
    const float e = __builtin_amdgcn_exp2f(-x * LOG2E);
    return __builtin_amdgcn_rcpf(1.0f + e);
}
__device__ __forceinline__ float fast_tanh(float x) {
    const float e = __builtin_amdgcn_exp2f(x * (2.0f * LOG2E));
    return 1.0f - 2.0f * __builtin_amdgcn_rcpf(e + 1.0f);
}

// ---------------------------------------------------------------------------
// Kernel 1: GRU over T=128, batch rows BJ=5120. 16 rows per block, 4 waves,
// each wave owns 32 cols of each of the 3 gates. Weights in register B-frags;
// h double-buffered in LDS (bf16); fp32 h in registers for the z*h term.
// ROUND 5: fast-math epilogue (v_rcp/v_exp) + branchless RNE bf16 cvt.
// ---------------------------------------------------------------------------
__global__ __launch_bounds__(256) void gru_kernel(
    const float* __restrict__ obs,   // [1024,128,5,64] fp32
    const float* __restrict__ W_ih,  // [384,64]
    const float* __restrict__ W_hh,  // [384,128]
    const float* __restrict__ b_ih,  // [384]
    const float* __restrict__ b_hh,  // [384]
    __hip_bfloat16* __restrict__ h_out)  // [5120,128] bf16 (internal ws)
{
    __shared__ alignas(16) short h_lds[2 * 16 * 136];

    const int tid = threadIdx.x;
    const int w = tid >> 6;          // wave 0..3
    const int lane = tid & 63;
    const int q = lane >> 4;         // quad 0..3
    const int c = lane & 15;
    const int r0 = blockIdx.x * 16;

    for (int i = tid; i < 2 * 16 * 136; i += 256) h_lds[i] = 0;

    // weight B-frags (fp32 -> bf16): B[k][n] = W[colbase+n][k], lane n=c, k=8q+j
    short8 wih[3][2][2];
    short8 whh[3][2][4];
#pragma unroll
    for (int g = 0; g < 3; ++g)
#pragma unroll
        for (int u = 0; u < 2; ++u) {
            const int col = g * 128 + w * 32 + u * 16 + c;
#pragma unroll
            for (int f = 0; f < 2; ++f) {
                const float4 a = *reinterpret_cast<const float4*>(W_ih + col * 64 + f * 32 + q * 8);
                const float4 b = *reinterpret_cast<const float4*>(W_ih + col * 64 + f * 32 + q * 8 + 4);
                wih[g][u][f] = cvt8(a, b);
            }
#pragma unroll
            for (int f = 0; f < 4; ++f) {
                const float4 a = *reinterpret_cast<const float4*>(W_hh + col * 128 + f * 32 + q * 8);
                const float4 b = *reinterpret_cast<const float4*>(W_hh + col * 128 + f * 32 + q * 8 + 4);
                whh[g][u][f] = cvt8(a, b);
            }
        }

    float bias_r[2], bias_z[2], bias_in[2], bias_hn[2];
#pragma unroll
    for (int u = 0; u < 2; ++u) {
        const int cc = w * 32 + u * 16 + c;
        bias_r[u]  = b_ih[cc]       + b_hh[cc];
        bias_z[u]  = b_ih[128 + cc] + b_hh[128 + cc];
        bias_in[u] = b_ih[256 + cc];
        bias_hn[u] = b_hh[256 + cc];
    }

    // x: A-frag lane holds row m=c (global row r0+c), k=32f+8q+j
    const int r = r0 + c;
    const int bb = r / 5;
    const int jj = r - bb * 5;
    const float* xg = obs + bb * 40960 + jj * 64 + q * 8;

    float h_keep[2][4];
#pragma unroll
    for (int u = 0; u < 2; ++u)
#pragma unroll
        for (int i = 0; i < 4; ++i) h_keep[u][i] = 0.0f;

    float4 xa0 = *reinterpret_cast<const float4*>(xg);
    float4 xa1 = *reinterpret_cast<const float4*>(xg + 4);
    float4 xa2 = *reinterpret_cast<const float4*>(xg + 32);
    float4 xa3 = *reinterpret_cast<const float4*>(xg + 36);
    short8 xc0 = cvt8(xa0, xa1);
    short8 xc1 = cvt8(xa2, xa3);

    __syncthreads();

    int bufo = 0;
    for (int t = 0; t < 128; ++t) {
        const int nbufo = 2176 - bufo;
        const short* hb = &h_lds[bufo];

        short8 hf[4];
#pragma unroll
        for (int f = 0; f < 4; ++f)
            hf[f] = *reinterpret_cast<const short8*>(hb + c * 136 + f * 32 + q * 8);

        const int tp = (t + 1) > 127 ? 127 : (t + 1);
        const float4 xb0 = *reinterpret_cast<const float4*>(xg + tp * 320);
        const float4 xb1 = *reinterpret_cast<const float4*>(xg + tp * 320 + 4);
        const float4 xb2 = *reinterpret_cast<const float4*>(xg + tp * 320 + 32);
        const float4 xb3 = *reinterpret_cast<const float4*>(xg + tp * 320 + 36);

        floatx4 ar[2], az[2], ain[2], ahn[2];
#pragma unroll
        for (int u = 0; u < 2; ++u) {
            ar[u]  = (floatx4){bias_r[u],  bias_r[u],  bias_r[u],  bias_r[u]};
            az[u]  = (floatx4){bias_z[u],  bias_z[u],  bias_z[u],  bias_z[u]};
            ain[u] = (floatx4){bias_in[u], bias_in[u], bias_in[u], bias_in[u]};
            ahn[u] = (floatx4){bias_hn[u], bias_hn[u], bias_hn[u], bias_hn[u]};
            ar[u]  = MFMA_BF16(xc0, wih[0][u][0], ar[u]);
            ar[u]  = MFMA_BF16(xc1, wih[0][u][1], ar[u]);
            az[u]  = MFMA_BF16(xc0, wih[1][u][0], az[u]);
            az[u]  = MFMA_BF16(xc1, wih[1][u][1], az[u]);
            ain[u] = MFMA_BF16(xc0, wih[2][u][0], ain[u]);
            ain[u] = MFMA_BF16(xc1, wih[2][u][1], ain[u]);
#pragma unroll
            for (int f = 0; f < 4; ++f) {
                ar[u]  = MFMA_BF16(hf[f], whh[0][u][f], ar[u]);
                az[u]  = MFMA_BF16(hf[f], whh[1][u][f], az[u]);
                ahn[u] = MFMA_BF16(hf[f], whh[2][u][f], ahn[u]);
            }
        }

        // GRU update; C/D layout: col=c, row=4q+i
        short* hnb = &h_lds[nbufo];
#pragma unroll
        for (int u = 0; u < 2; ++u)
#pragma unroll
            for (int i = 0; i < 4; ++i) {
                const float rr = fast_sigmoid(ar[u][i]);
                const float zz = fast_sigmoid(az[u][i]);
                const float nn = fast_tanh(ain[u][i] + rr * ahn[u][i]);
                const float hv = nn + zz * (h_keep[u][i] - nn);
                h_keep[u][i] = hv;
                hnb[(4 * q + i) * 136 + w * 32 + u * 16 + c] = bf16_s(hv);
            }

        xc0 = cvt8(xb0, xb1);
        xc1 = cvt8(xb2, xb3);
        bufo = nbufo;
        __syncthreads();
    }

#pragma unroll
    for (int u = 0; u < 2; ++u)
#pragma unroll
        for (int i = 0; i < 4; ++i)
            h_out[(r0 + 4 * q + i) * 128 + w * 32 + u * 16 + c] = __float2bfloat16(h_keep[u][i]);
}

// ---------------------------------------------------------------------------
// Kernel 2: GAT + trunk MLP + actor/critic. One block per 4 batches (20 rows).
// ROUND 5: matmuls restructured for W-reuse — thread owns (col, 10-row strip),
// per k: 1 coalesced W load + broadcast LDS hs reads + 10 fma. hs reads are
// wave-uniform addresses (whole wave same row/k) -> LDS broadcast, free.
// ---------------------------------------------------------------------------
__global__ __launch_bounds__(256) void head_kernel(
    const __hip_bfloat16* __restrict__ h_in,  // [5120,128] bf16 ws
    const float* __restrict__ gat_W,    // [128,128]
    const float* __restrict__ att_src,  // [4,32]
    const float* __restrict__ att_dst,  // [4,32]
    const float* __restrict__ gat_b,    // [128]
    const float* __restrict__ W1,       // [128,128]
    const float* __restrict__ b1,       // [128]
    const float* __restrict__ W2,       // [128,64]
    const float* __restrict__ b2,       // [64]
    const float* __restrict__ actor_W,  // [5,64,4]
    const float* __restrict__ actor_b,  // [5,4]
    const float* __restrict__ critic_W, // [64]
    const float* __restrict__ critic_b, // [1]
    float* __restrict__ out)            // logits[1024*5*4] ++ value[1024], fp32
{
    __shared__ float hs[20][128];
    __shared__ float xp[20][128];
    __shared__ float gs[20][128];
    __shared__ float t1[20][128];
    __shared__ float t2[20][64];
    __shared__ float as_[20][4];
    __shared__ float ad_[20][4];

    const int tid = threadIdx.x;
    const int b0 = blockIdx.x * 4;
    const int rbase = b0 * 5;

    for (int i = tid; i < 20 * 128; i += 256)
        hs[i >> 7][i & 127] = bf2f(h_in[rbase * 128 + i]);
    __syncthreads();

    // ---- xp = h @ gat_W : col = tid&127, rows half*10..half*10+9
    {
        const int col = tid & 127;
        const int half = tid >> 7;
        float acc[10];
#pragma unroll
        for (int i = 0; i < 10; ++i) acc[i] = 0.0f;
#pragma unroll 4
        for (int k = 0; k < 128; ++k) {
            const float wv = gat_W[k * 128 + col];
#pragma unroll
            for (int i = 0; i < 10; ++i)
                acc[i] += hs[half * 10 + i][k] * wv;
        }
#pragma unroll
        for (int i = 0; i < 10; ++i) xp[half * 10 + i][col] = acc[i];
    }
    __syncthreads();

    // per-node attention scores
    if (tid < 160) {
        const int row = tid >> 3;
        const int hd = (tid >> 1) & 3;
        const int which = tid & 1;
        const float* att = which ? att_dst : att_src;
        float acc = 0.0f;
#pragma unroll
        for (int d = 0; d < 32; ++d) acc += xp[row][hd * 32 + d] * att[hd * 32 + d];
        if (which) ad_[row][hd] = acc; else as_[row][hd] = acc;
    }
    __syncthreads();

    // softmax over chain neighbors {i-1,i,i+1} and aggregate
    for (int i = tid; i < 20 * 128; i += 256) {
        const int row = i >> 7, col = i & 127, hd = col >> 5;
        const int bb = row / 5, dst = row - bb * 5, jbase = bb * 5;
        const float adv = ad_[row][hd];
        float ev[3]; int js[3]; int cnt = 0; float mx = -1e30f;
#pragma unroll
        for (int dj = -1; dj <= 1; ++dj) {
            const int j = dst + dj;
            if (j < 0 || j >= 5) continue;
            float e = as_[jbase + j][hd] + adv;
            e = e > 0.0f ? e : 0.2f * e;   // leaky_relu 0.2
            js[cnt] = j; ev[cnt] = e; mx = fmaxf(mx, e); ++cnt;
        }
        float s = 0.0f, num = 0.0f;
        for (int k = 0; k < cnt; ++k) {
            const float a = __builtin_amdgcn_exp2f((ev[k] - mx) * LOG2E);
            s += a; num += a * xp[jbase + js[k]][col];
        }
        gs[row][col] = num * __builtin_amdgcn_rcpf(s) + gat_b[col];
    }
    __syncthreads();

    // ---- t1 = relu(g @ W1 + b1)
    {
        const int col = tid & 127;
        const int half = tid >> 7;
        float acc[10];
#pragma unroll
        for (int i = 0; i < 10; ++i) acc[i] = 0.0f;
#pragma unroll 4
        for (int k = 0; k < 128; ++k) {
            const float wv = W1[k * 128 + col];
#pragma unroll
            for (int i = 0; i < 10; ++i)
                acc[i] += gs[half * 10 + i][k] * wv;
        }
        const float bv = b1[col];
#pragma unroll
        for (int i = 0; i < 10; ++i)
            t1[half * 10 + i][col] = fmaxf(acc[i] + bv, 0.0f);
    }
    __syncthreads();

    // ---- t2 = relu(t1 @ W2 + b2) : col = tid&63, rows quarter*5..quarter*5+4
    {
        const int col = tid & 63;
        const int quarter = tid >> 6;
        float acc[5];
#pragma unroll
        for (int i = 0; i < 5; ++i) acc[i] = 0.0f;
#pragma unroll 4
        for (int k = 0; k < 128; ++k) {
            const float wv = W2[k * 64 + col];
#pragma unroll
            for (int i = 0; i < 5; ++i)
                acc[i] += t1[quarter * 5 + i][k] * wv;
        }
        const float bv = b2[col];
#pragma unroll
        for (int i = 0; i < 5; ++i)
            t2[quarter * 5 + i][col] = fmaxf(acc[i] + bv, 0.0f);
    }
    __syncthreads();

    // actor logits
    if (tid < 80) {
        const int row = tid >> 2, p = tid & 3;
        const int j = row % 5;
        float acc = actor_b[j * 4 + p];
#pragma unroll
        for (int o = 0; o < 64; ++o)
            acc += t2[row][o] * actor_W[j * 256 + o * 4 + p];
        out[(rbase + row) * 4 + p] = acc;
    }
    // critic on junction mean
    if (tid >= 128 && tid < 132) {
        const int bb = tid - 128;
        float acc = 0.0f;
#pragma unroll
        for (int o = 0; o < 64; ++o) {
            float m = 0.0f;
#pragma unroll
            for (int j = 0; j < 5; ++j) m += t2[bb * 5 + j][o];
            acc += (m * 0.2f) * critic_W[o];
        }
        out[20480 + b0 + bb] = acc + critic_b[0];
    }
}

extern "C" void kernel_launch(void* const* d_in, const int* in_sizes, int n_in,
                              void* d_out, int out_size, void* d_ws, size_t ws_size,
                              hipStream_t stream) {
    (void)in_sizes; (void)n_in; (void)out_size; (void)ws_size;
    const float* obs      = (const float*)d_in[0];
    // d_in[1] = edge_index (fixed bidirectional 5-chain baked into kernel 2)
    const float* W_ih     = (const float*)d_in[2];
    const float* W_hh     = (const float*)d_in[3];
    const float* b_ih     = (const float*)d_in[4];
    const float* b_hh     = (const float*)d_in[5];
    const float* gat_W    = (const float*)d_in[6];
    const float* att_src  = (const float*)d_in[7];
    const float* att_dst  = (const float*)d_in[8];
    const float* gat_b    = (const float*)d_in[9];
    const float* W1       = (const float*)d_in[10];
    const float* b1       = (const float*)d_in[11];
    const float* W2       = (const float*)d_in[12];
    const float* b2       = (const float*)d_in[13];
    const float* actor_W  = (const float*)d_in[14];
    const float* actor_b  = (const float*)d_in[15];
    const float* critic_W = (const float*)d_in[16];
    const float* critic_b = (const float*)d_in[17];

    __hip_bfloat16* h_ws = (__hip_bfloat16*)d_ws;  // [5120,128] bf16 = 1.31 MB

    gru_kernel<<<320, 256, 0, stream>>>(obs, W_ih, W_hh, b_ih, b_hh, h_ws);
    head_kernel<<<256, 256, 0, stream>>>(h_ws, gat_W, att_src, att_dst, gat_b,
                                         W1, b1, W2, b2, actor_W, actor_b,
                                         critic_W, critic_b,
                                         (float*)d_out);
}

// Round 7
// 427.260 us; speedup vs baseline: 1.6172x; 1.2964x over previous
//
#include <hip/hip_runtime.h>
#include <hip/hip_bf16.h>

typedef short shortx4 __attribute__((ext_vector_type(4)));
typedef short short8 __attribute__((ext_vector_type(8)));
typedef float floatx4 __attribute__((ext_vector_type(4)));

#define MFMA_BF16(A, B, C) __builtin_amdgcn_mfma_f32_16x16x32_bf16((A), (B), (C), 0, 0, 0)
#define LOG2E 1.44269504088896340736f

__device__ __forceinline__ float bf2f(const __hip_bfloat16 v) { return __bfloat162float(v); }

// branchless RNE fp32->bf16 (inputs finite by construction)
__device__ __forceinline__ unsigned rne_bits(float f) {
    unsigned u = __builtin_bit_cast(unsigned, f);
    return u + 0x7fffu + ((u >> 16) & 1u);
}
__device__ __forceinline__ unsigned pack_bf16(float a, float b) {
    return (rne_bits(b) & 0xffff0000u) | (rne_bits(a) >> 16);
}
__device__ __forceinline__ short bf16_s(float f) { return (short)(rne_bits(f) >> 16); }

__device__ __forceinline__ short8 cvt8(const float4 a, const float4 b) {
    union { unsigned u[4]; short8 s; } r;
    r.u[0] = pack_bf16(a.x, a.y);
    r.u[1] = pack_bf16(a.z, a.w);
    r.u[2] = pack_bf16(b.x, b.y);
    r.u[3] = pack_bf16(b.z, b.w);
    return r.s;
}

// assemble short8 MFMA frag from two 8B-aligned LDS reads
__device__ __forceinline__ short8 ld_s8(const short* p) {
    union { struct { shortx4 lo, hi; } p; short8 v; } u;
    u.p.lo = *reinterpret_cast<const shortx4*>(p);
    u.p.hi = *reinterpret_cast<const shortx4*>(p + 4);
    return u.v;
}

__device__ __forceinline__ float fast_sigmoid(float x) {
    const float e = __builtin_amdgcn_exp2f(-x * LOG2E);
    return __builtin_amdgcn_rcpf(1.0f + e);
}
__device__ __forceinline__ float fast_tanh(float x) {
    const float e = __builtin_amdgcn_exp2f(x * (2.0f * LOG2E));
    return 1.0f - 2.0f * __builtin_amdgcn_rcpf(e + 1.0f);
}

// ---------------------------------------------------------------------------
// Kernel 1: GRU, 16 rows/block, 512 threads = 8 waves; wave w owns cols
// w*16..w*16+15 of each of the 3 gates. Weights in register B-frags; bias as
// MFMA C operand. h double-buffered in LDS stride 132 shorts (bank-balanced);
// x staged to LDS in bf16 once per block per step (stride 68), value
// prefetched one step ahead in registers.
// ---------------------------------------------------------------------------
__global__ __launch_bounds__(512) void gru_kernel(
    const float* __restrict__ obs,   // [1024,128,5,64] fp32
    const float* __restrict__ W_ih,  // [384,64]
    const float* __restrict__ W_hh,  // [384,128]
    const float* __restrict__ b_ih,  // [384]
    const float* __restrict__ b_hh,  // [384]
    __hip_bfloat16* __restrict__ h_out)  // [5120,128] bf16 (internal ws)
{
    __shared__ alignas(16) short h_lds[2 * 16 * 132];  // 2 bufs x 16 rows x 132
    __shared__ alignas(16) short x_lds[2 * 16 * 68];   // 2 bufs x 16 rows x 68

    const int tid = threadIdx.x;
    const int w = tid >> 6;          // wave 0..7
    const int lane = tid & 63;
    const int q = lane >> 4;         // quad 0..3
    const int c = lane & 15;
    const int r0 = blockIdx.x * 16;

    for (int i = tid; i < 2 * 16 * 132; i += 512) h_lds[i] = 0;

    // weight B-frags: B[k][n] = W[col][k], lane n=c, k=8q+j (+32 per frag)
    short8 wih[3][2];
    short8 whh[3][4];
#pragma unroll
    for (int g = 0; g < 3; ++g) {
        const int col = g * 128 + w * 16 + c;
#pragma unroll
        for (int f = 0; f < 2; ++f) {
            const float4 a = *reinterpret_cast<const float4*>(W_ih + col * 64 + f * 32 + q * 8);
            const float4 b = *reinterpret_cast<const float4*>(W_ih + col * 64 + f * 32 + q * 8 + 4);
            wih[g][f] = cvt8(a, b);
        }
#pragma unroll
        for (int f = 0; f < 4; ++f) {
            const float4 a = *reinterpret_cast<const float4*>(W_hh + col * 128 + f * 32 + q * 8);
            const float4 b = *reinterpret_cast<const float4*>(W_hh + col * 128 + f * 32 + q * 8 + 4);
            whh[g][f] = cvt8(a, b);
        }
    }

    // bias as MFMA C operands (same col for all 4 acc rows)
    const int cc = w * 16 + c;
    const float br_ = b_ih[cc] + b_hh[cc];
    const float bz_ = b_ih[128 + cc] + b_hh[128 + cc];
    const float bin_ = b_ih[256 + cc];
    const float bhn_ = b_hh[256 + cc];
    const floatx4 cbias_r  = {br_, br_, br_, br_};
    const floatx4 cbias_z  = {bz_, bz_, bz_, bz_};
    const floatx4 cbias_in = {bin_, bin_, bin_, bin_};
    const floatx4 cbias_hn = {bhn_, bhn_, bhn_, bhn_};

    // x staging: thread (srow=tid>>5, scp=tid&31) loads obs[r0+srow][t][2scp..2scp+1]
    const int srow = tid >> 5, scp = tid & 31;
    {
        const int rs = r0 + srow;
        const int bbs = rs / 5;
        const int jjs = rs - bbs * 5;
        const float* xgs = obs + bbs * 40960 + jjs * 64 + scp * 2;
        unsigned* xb32 = reinterpret_cast<unsigned*>(x_lds);
        // stage t=0 into buf 0
        const float2 v0 = *reinterpret_cast<const float2*>(xgs);
        xb32[srow * 34 + scp] = pack_bf16(v0.x, v0.y);
        // prefetch t=1 value into regs (written inside loop)
        float2 vn = *reinterpret_cast<const float2*>(xgs + 320);

        float h_keep[4] = {0.0f, 0.0f, 0.0f, 0.0f};

        __syncthreads();  // h zeroed + x(t=0) staged

        int bufo = 0;       // h buffer offset (shorts)
        for (int t = 0; t < 128; ++t) {
            const int nbufo = 2112 - bufo;           // 16*132 = 2112
            const short* hb = &h_lds[bufo];
            const short* xb = &x_lds[(t & 1) * 1088];  // 16*68 = 1088

            // x A-frags: lane row m=c, k=8q+j (+32)
            const short8 xc0 = ld_s8(xb + c * 68 + q * 8);
            const short8 xc1 = ld_s8(xb + c * 68 + 32 + q * 8);
            // h A-frags
            short8 hf[4];
#pragma unroll
            for (int f = 0; f < 4; ++f)
                hf[f] = ld_s8(hb + c * 132 + f * 32 + q * 8);

            // stage x(t+1) from last iter's regs; prefetch x(t+2)
            unsigned* xw = reinterpret_cast<unsigned*>(&x_lds[((t + 1) & 1) * 1088]);
            xw[srow * 34 + scp] = pack_bf16(vn.x, vn.y);
            const int tp = (t + 2) > 127 ? 127 : (t + 2);
            vn = *reinterpret_cast<const float2*>(xgs + tp * 320);

            // gates
            floatx4 ar  = MFMA_BF16(xc0, wih[0][0], cbias_r);
            floatx4 az  = MFMA_BF16(xc0, wih[1][0], cbias_z);
            floatx4 ain = MFMA_BF16(xc0, wih[2][0], cbias_in);
            ar  = MFMA_BF16(xc1, wih[0][1], ar);
            az  = MFMA_BF16(xc1, wih[1][1], az);
            ain = MFMA_BF16(xc1, wih[2][1], ain);
            floatx4 ahn = MFMA_BF16(hf[0], whh[2][0], cbias_hn);
#pragma unroll
            for (int f = 0; f < 4; ++f) {
                ar = MFMA_BF16(hf[f], whh[0][f], ar);
                az = MFMA_BF16(hf[f], whh[1][f], az);
                if (f > 0) ahn = MFMA_BF16(hf[f], whh[2][f], ahn);
            }

            // GRU update; C/D layout: col=c, row=4q+i
            short* hnb = &h_lds[nbufo];
#pragma unroll
            for (int i = 0; i < 4; ++i) {
                const float rr = fast_sigmoid(ar[i]);
                const float zz = fast_sigmoid(az[i]);
                const float nn = fast_tanh(ain[i] + rr * ahn[i]);
                const float hv = nn + zz * (h_keep[i] - nn);
                h_keep[i] = hv;
                hnb[(4 * q + i) * 132 + w * 16 + c] = bf16_s(hv);
            }

            bufo = nbufo;
            __syncthreads();
        }

        // final hidden -> global ws (bf16): rows r0+4q+i, col w*16+c
#pragma unroll
        for (int i = 0; i < 4; ++i)
            h_out[(r0 + 4 * q + i) * 128 + w * 16 + c] = __float2bfloat16(h_keep[i]);
    }
}

// ---------------------------------------------------------------------------
// Kernel 2: GAT + trunk MLP + actor/critic. ONE BLOCK PER BATCH (1024 blocks,
// 4 blocks/CU = 16 waves/CU). Matmuls K-split across threads + LDS reduce so
// all 256 threads work and load chains are short.
// ---------------------------------------------------------------------------
__global__ __launch_bounds__(256) void head_kernel(
    const __hip_bfloat16* __restrict__ h_in,  // [5120,128] bf16 ws
    const float* __restrict__ gat_W,    // [128,128]
    const float* __restrict__ att_src,  // [4,32]
    const float* __restrict__ att_dst,  // [4,32]
    const float* __restrict__ gat_b,    // [128]
    const float* __restrict__ W1,       // [128,128]
    const float* __restrict__ b1,       // [128]
    const float* __restrict__ W2,       // [128,64]
    const float* __restrict__ b2,       // [64]
    const float* __restrict__ actor_W,  // [5,64,4]
    const float* __restrict__ actor_b,  // [5,4]
    const float* __restrict__ critic_W, // [64]
    const float* __restrict__ critic_b, // [1]
    float* __restrict__ out)            // logits[1024*5*4] ++ value[1024], fp32
{
    __shared__ float hs[5][128];
    __shared__ float xp[5][128];
    __shared__ float gs[5][128];
    __shared__ float t1[5][128];
    __shared__ float t2[5][64];
    __shared__ float pp[1280];          // K-split partials (reused per stage)
    __shared__ float as_[5][4];
    __shared__ float ad_[5][4];

    const int tid = threadIdx.x;
    const int b = blockIdx.x;

    // load h (5 rows x 128)
    for (int i = tid; i < 640; i += 256)
        hs[i >> 7][i & 127] = bf2f(h_in[b * 640 + i]);
    __syncthreads();

    // ---- xp = h @ gat_W : thread (kh=tid>>7, col=tid&127), K-half of 64
    {
        const int kh = tid >> 7, col = tid & 127;
        float acc[5] = {0, 0, 0, 0, 0};
#pragma unroll 8
        for (int k2 = 0; k2 < 64; ++k2) {
            const int k = kh * 64 + k2;
            const float wv = gat_W[k * 128 + col];
#pragma unroll
            for (int i = 0; i < 5; ++i) acc[i] += hs[i][k] * wv;
        }
#pragma unroll
        for (int i = 0; i < 5; ++i) pp[kh * 640 + i * 128 + col] = acc[i];
    }
    __syncthreads();
    for (int i = tid; i < 640; i += 256)
        xp[i >> 7][i & 127] = pp[i] + pp[640 + i];
    __syncthreads();

    // per-node attention scores (5 rows x 4 heads x {src,dst} = 40)
    if (tid < 40) {
        const int row = tid >> 3;
        const int hd = (tid >> 1) & 3;
        const int which = tid & 1;
        const float* att = which ? att_dst : att_src;
        float acc = 0.0f;
#pragma unroll
        for (int d = 0; d < 32; ++d) acc += xp[row][hd * 32 + d] * att[hd * 32 + d];
        if (which) ad_[row][hd] = acc; else as_[row][hd] = acc;
    }
    __syncthreads();

    // softmax over chain neighbors {i-1,i,i+1} and aggregate
    for (int i = tid; i < 640; i += 256) {
        const int dst = i >> 7, col = i & 127, hd = col >> 5;
        const float adv = ad_[dst][hd];
        float ev[3]; int js[3]; int cnt = 0; float mx = -1e30f;
#pragma unroll
        for (int dj = -1; dj <= 1; ++dj) {
            const int j = dst + dj;
            if (j < 0 || j >= 5) continue;
            float e = as_[j][hd] + adv;
            e = e > 0.0f ? e : 0.2f * e;   // leaky_relu 0.2
            js[cnt] = j; ev[cnt] = e; mx = fmaxf(mx, e); ++cnt;
        }
        float s = 0.0f, num = 0.0f;
        for (int k = 0; k < cnt; ++k) {
            const float a = __builtin_amdgcn_exp2f((ev[k] - mx) * LOG2E);
            s += a; num += a * xp[js[k]][col];
        }
        gs[dst][col] = num * __builtin_amdgcn_rcpf(s) + gat_b[col];
    }
    __syncthreads();

    // ---- t1 = relu(g @ W1 + b1) : same K-split
    {
        const int kh = tid >> 7, col = tid & 127;
        float acc[5] = {0, 0, 0, 0, 0};
#pragma unroll 8
        for (int k2 = 0; k2 < 64; ++k2) {
            const int k = kh * 64 + k2;
            const float wv = W1[k * 128 + col];
#pragma unroll
            for (int i = 0; i < 5; ++i) acc[i] += gs[i][k] * wv;
        }
#pragma unroll
        for (int i = 0; i < 5; ++i) pp[kh * 640 + i * 128 + col] = acc[i];
    }
    __syncthreads();
    for (int i = tid; i < 640; i += 256)
        t1[i >> 7][i & 127] = fmaxf(pp[i] + pp[640 + i] + b1[i & 127], 0.0f);
    __syncthreads();

    // ---- t2 = relu(t1 @ W2 + b2) : thread (kq=tid>>6, col=tid&63), K-quarter 32
    {
        const int kq = tid >> 6, col = tid & 63;
        float acc[5] = {0, 0, 0, 0, 0};
#pragma unroll 8
        for (int k2 = 0; k2 < 32; ++k2) {
            const int k = kq * 32 + k2;
            const float wv = W2[k * 64 + col];
#pragma unroll
            for (int i = 0; i < 5; ++i) acc[i] += t1[i][k] * wv;
        }
#pragma unroll
        for (int i = 0; i < 5; ++i) pp[kq * 320 + i * 64 + col] = acc[i];
    }
    __syncthreads();
    for (int i = tid; i < 320; i += 256) {
        const int row = i >> 6, col = i & 63;
        t2[row][col] = fmaxf(pp[i] + pp[320 + i] + pp[640 + i] + pp[960 + i] + b2[col], 0.0f);
    }
    __syncthreads();

    // actor logits: 5 rows x 4 p
    if (tid < 20) {
        const int row = tid >> 2, p = tid & 3;
        float acc = actor_b[row * 4 + p];
#pragma unroll
        for (int o = 0; o < 64; ++o)
            acc += t2[row][o] * actor_W[row * 256 + o * 4 + p];
        out[(b * 5 + row) * 4 + p] = acc;
    }
    // critic on junction mean
    if (tid == 64) {
        float acc = 0.0f;
#pragma unroll
        for (int o = 0; o < 64; ++o) {
            float m = 0.0f;
#pragma unroll
            for (int j = 0; j < 5; ++j) m += t2[j][o];
            acc += (m * 0.2f) * critic_W[o];
        }
        out[20480 + b] = acc + critic_b[0];
    }
}

extern "C" void kernel_launch(void* const* d_in, const int* in_sizes, int n_in,
                              void* d_out, int out_size, void* d_ws, size_t ws_size,
                              hipStream_t stream) {
    (void)in_sizes; (void)n_in; (void)out_size; (void)ws_size;
    const float* obs      = (const float*)d_in[0];
    // d_in[1] = edge_index (fixed bidirectional 5-chain baked into kernel 2)
    const float* W_ih     = (const float*)d_in[2];
    const float* W_hh     = (const float*)d_in[3];
    const float* b_ih     = (const float*)d_in[4];
    const float* b_hh     = (const float*)d_in[5];
    const float* gat_W    = (const float*)d_in[6];
    const float* att_src  = (const float*)d_in[7];
    const float* att_dst  = (const float*)d_in[8];
    const float* gat_b    = (const float*)d_in[9];
    const float* W1       = (const float*)d_in[10];
    const float* b1       = (const float*)d_in[11];
    const float* W2       = (const float*)d_in[12];
    const float* b2       = (const float*)d_in[13];
    const float* actor_W  = (const float*)d_in[14];
    const float* actor_b  = (const float*)d_in[15];
    const float* critic_W = (const float*)d_in[16];
    const float* critic_b = (const float*)d_in[17];

    __hip_bfloat16* h_ws = (__hip_bfloat16*)d_ws;  // [5120,128] bf16 = 1.31 MB

    gru_kernel<<<320, 512, 0, stream>>>(obs, W_ih, W_hh, b_ih, b_hh, h_ws);
    head_kernel<<<1024, 256, 0, stream>>>(h_ws, gat_W, att_src, att_dst, gat_b,
                                          W1, b1, W2, b2, actor_W, actor_b,
                                          critic_W, critic_b,
                                          (float*)d_out);
}